// Round 2
// baseline (572.078 us; speedup 1.0000x reference)
//
#include <hip/hip_runtime.h>
#include <hip/hip_fp16.h>
#include <hip/hip_cooperative_groups.h>
#include <math.h>

#define NN      100000
#define EE      1600000
#define NPAIRS  800000
#define DIN     128
#define CC      16
#define NITERS  5
#define NBLKS   100000               // 16-edge mfma blocks
#define NEGLOGC (-2.772588722239781f)
#define FPSCALE 1048576.0f           // 2^20 fixed-point scale (agg)
#define FPINV   (1.0f / 1048576.0f)

// ---- fallback (round-0 verified) config ----
#define UU      4                    // mfma blocks per wave
#define GRID_E  (NBLKS / (UU * 4))   // 6250 blocks of 256 (4 waves)

// ---- cooperative config: 2 blocks/CU on 256 CUs = 512 (2x margin vs 4/CU) ----
#define CPBLK   512
#define CNW     (CPBLK * 4)          // 2048 waves
#define CUU     49                   // ceil(NBLKS / CNW)
#define CTAILW  (NBLKS - (CUU - 1) * CNW)   // 1696
#define CNTHR   (CPBLK * 256)        // 131072

#if __has_builtin(__builtin_amdgcn_mfma_f32_16x16x16bf16_1k)
#define USE_1K 1
#else
#define USE_1K 0
#endif

namespace cg = cooperative_groups;

typedef float f4  __attribute__((ext_vector_type(4)));
typedef float v4f __attribute__((ext_vector_type(4)));
typedef short v4s __attribute__((ext_vector_type(4)));
typedef short v8s __attribute__((ext_vector_type(8)));
typedef unsigned int u4v __attribute__((ext_vector_type(4)));
typedef int  i4v __attribute__((ext_vector_type(4)));
typedef unsigned long long ull;

// ---------------------------------------------------------------------------
// helpers: fp16 / bf16 <-> f32
// ---------------------------------------------------------------------------
__device__ __forceinline__ unsigned short f2h(float f) {
    return __half_as_ushort(__float2half(f));
}
__device__ __forceinline__ float h2f(unsigned short u) {
    return __half2float(__ushort_as_half(u));
}
__device__ __forceinline__ unsigned int pack_h(float lo, float hi) {
    return (unsigned int)f2h(lo) | ((unsigned int)f2h(hi) << 16);
}
__device__ __forceinline__ unsigned short f2bf(float f) {
    unsigned int u = __float_as_uint(f);
    unsigned int r = u + 0x7fffu + ((u >> 16) & 1u);   // round-nearest-even
    return (unsigned short)(r >> 16);
}

// ---------------------------------------------------------------------------
// fused setup: M = sigmoid(10*param) (+ row sums at M[256..271]);
// logb0 = log_softmax(x@W+b); agg = 0.   grid = 6250 x 256 (covers NN*CC)
// ---------------------------------------------------------------------------
__global__ __launch_bounds__(256) void k_setup(
    const float* __restrict__ x, const float* __restrict__ W,
    const float* __restrict__ b, const float* __restrict__ param,
    float* __restrict__ M, float* __restrict__ logb0,
    unsigned int* __restrict__ agg32)
{
    if (blockIdx.x == 0) {
        if (threadIdx.x < CC * (CC + 1) / 2) {
            int i = threadIdx.x;
            int r = 0;
            while ((r + 1) * (r + 2) / 2 <= i) ++r;
            int c = i - r * (r + 1) / 2;
            float z = param[i] * 10.0f;
            float s = 1.0f / (1.0f + __expf(-z));
            M[r * CC + c] = s;
            if (r != c) M[c * CC + r] = s;
        }
        __syncthreads();                       // block-0-local barrier
        if (threadIdx.x < CC) {                // row sums for the T shortcut
            float s = 0.f;
            for (int c = 0; c < CC; ++c) s += M[threadIdx.x * CC + c];
            M[256 + threadIdx.x] = s;
        }
    }

    int idx = blockIdx.x * 256 + threadIdx.x;
    agg32[idx] = 0u;

    int node = idx >> 4;
    int cls  = idx & 15;
    const f4* xr4 = (const f4*)(x + (long)node * DIN);
    float acc = b[cls];
#pragma unroll 8
    for (int k4 = 0; k4 < DIN / 4; ++k4) {
        f4 xv = __builtin_nontemporal_load(xr4 + k4);   // x streamed once
        acc = fmaf(xv.x, W[(4 * k4 + 0) * CC + cls], acc);
        acc = fmaf(xv.y, W[(4 * k4 + 1) * CC + cls], acc);
        acc = fmaf(xv.z, W[(4 * k4 + 2) * CC + cls], acc);
        acc = fmaf(xv.w, W[(4 * k4 + 3) * CC + cls], acc);
    }
    float m = acc;
    for (int off = 8; off; off >>= 1) m = fmaxf(m, __shfl_xor(m, off, 16));
    float s = __expf(acc - m);
    for (int off = 8; off; off >>= 1) s += __shfl_xor(s, off, 16);
    logb0[idx] = acc - m - __logf(s);
}

// ---------------------------------------------------------------------------
// Persistent cooperative BP kernel (512 blocks, 2/CU — 2x co-residency margin).
// Messages live in registers: reverse message of edge m is at lane m^1 of the
// SAME wave (pairs are adjacent edges), as packed fp16 in mo0/mo1[CUU].
// Swapped MFMA (D = M * E^T) puts output directly in edge-per-lane layout.
// ---------------------------------------------------------------------------
__global__ __launch_bounds__(256, 2) void k_bp(
    const int* __restrict__ esrc, const int* __restrict__ edst,
    const float* __restrict__ logb0, const float* __restrict__ Mg,
    unsigned int* __restrict__ agg32, float* __restrict__ logb,
    float* __restrict__ out)
{
    const int lane = threadIdx.x & 63;
    const int wid  = blockIdx.x * 4 + (threadIdx.x >> 6);
    const int tid  = blockIdx.x * 256 + threadIdx.x;
    const int m    = lane & 15;
    const int q    = lane >> 4;

    ull* agg8 = (ull*)agg32;
    cg::grid_group grid = cg::this_grid();

#if USE_1K
    // A-operand fragment: A[row=m][k=4q+j] = M[m][4q+j]
    v4s mfrag;
#pragma unroll
    for (int j = 0; j < 4; ++j)
        mfrag[j] = (short)f2bf(Mg[m * CC + 4 * q + j]);
#endif
    f4 rs = *(const f4*)(Mg + 256 + 4 * q);    // rowsums for k = 4q..4q+3

    // persistent reverse-messages, packed fp16: classes (4q,4q+1),(4q+2,4q+3)
    // of edge m.  Uniform init shift cancels exactly under normalization.
    unsigned int mo0[CUU], mo1[CUU];
    {
        const unsigned int initm = pack_h(NEGLOGC, NEGLOGC);
#pragma unroll
        for (int k = 0; k < CUU; ++k) { mo0[k] = initm; mo1[k] = initm; }
    }

    const float* curb = logb0;

#pragma unroll 1
    for (int it = 0; it < NITERS; ++it) {
        // ================= edge phase =================
#pragma unroll
        for (int c0 = 0; c0 < CUU; c0 += 4) {
            int srcv[4], dstv[4];
            f4 lb[4];
            // hoist chain heads: edge indices (4 independent chains)
#pragma unroll
            for (int u = 0; u < 4; ++u) {
                const int k = c0 + u;
                if (k < CUU) {
                    const bool act = (k < CUU - 1) || (wid < CTAILW);
                    if (act) {
                        const long eb = ((long)wid + (long)k * CNW) * 16;
                        srcv[u] = esrc[eb + m];
                        dstv[u] = edst[eb + m];
                    }
                }
            }
            // dependent gathers, still before any compute
#pragma unroll
            for (int u = 0; u < 4; ++u) {
                const int k = c0 + u;
                if (k < CUU) {
                    const bool act = (k < CUU - 1) || (wid < CTAILW);
                    if (act) lb[u] = *(const f4*)(curb + (long)srcv[u] * CC + 4 * q);
                }
            }
            // compute
#pragma unroll
            for (int u = 0; u < 4; ++u) {
                const int k = c0 + u;
                if (k >= CUU) continue;
                const bool act = (k < CUU - 1) || (wid < CTAILW);
                if (!act) continue;

                float mv0 = h2f((unsigned short)(mo0[k] & 0xffffu));
                float mv1 = h2f((unsigned short)(mo0[k] >> 16));
                float mv2 = h2f((unsigned short)(mo1[k] & 0xffffu));
                float mv3 = h2f((unsigned short)(mo1[k] >> 16));

                float e0 = __expf(lb[u].x - mv0);   // t = logb[src] - msg[rev]
                float e1 = __expf(lb[u].y - mv1);
                float e2 = __expf(lb[u].z - mv2);
                float e3 = __expf(lb[u].w - mv3);

                float Tm = e0 * rs.x;
                Tm = fmaf(e1, rs.y, Tm);
                Tm = fmaf(e2, rs.z, Tm);
                Tm = fmaf(e3, rs.w, Tm);
                Tm += __shfl_xor(Tm, 16, 64);
                Tm += __shfl_xor(Tm, 32, 64);
                float lT = __logf(Tm);             // log T[edge m], lane-local

                float D0, D1, D2, D3;
#if USE_1K
                v4s a;
                a[0] = (short)f2bf(e0); a[1] = (short)f2bf(e1);
                a[2] = (short)f2bf(e2); a[3] = (short)f2bf(e3);
                v4f acc = {0.f, 0.f, 0.f, 0.f};
                // swapped operands: D[row=class 4q+i][col=edge m]
                v4f D = __builtin_amdgcn_mfma_f32_16x16x16bf16_1k(mfrag, a, acc, 0, 0, 0);
                D0 = D[0]; D1 = D[1]; D2 = D[2]; D3 = D[3];
#else
                // correctness fallback: cross-quad broadcast + scalar dot
                float ee[4] = {e0, e1, e2, e3};
                float g1[4], g2[4], g3[4];
#pragma unroll
                for (int j = 0; j < 4; ++j) {
                    g1[j] = __shfl_xor(ee[j], 16, 64);
                    g2[j] = __shfl_xor(ee[j], 32, 64);
                    g3[j] = __shfl_xor(ee[j], 48, 64);
                }
                float Dv[4];
#pragma unroll
                for (int i = 0; i < 4; ++i) {
                    const float* Mr = Mg + (4 * q + i) * CC;
                    float d = 0.f;
#pragma unroll
                    for (int j = 0; j < 4; ++j) {
                        d = fmaf(Mr[4 * q + j],       ee[j], d);
                        d = fmaf(Mr[4 * (q ^ 1) + j], g1[j], d);
                        d = fmaf(Mr[4 * (q ^ 2) + j], g2[j], d);
                        d = fmaf(Mr[4 * (q ^ 3) + j], g3[j], d);
                    }
                    Dv[i] = d;
                }
                D0 = Dv[0]; D1 = Dv[1]; D2 = Dv[2]; D3 = Dv[3];
#endif
                float n0 = __logf(D0) - lT;
                float n1 = __logf(D1) - lT;
                float n2 = __logf(D2) - lT;
                float n3 = __logf(D3) - lT;

                unsigned int q0 = (unsigned int)(fmaxf(-n0, 0.f) * FPSCALE + 0.5f);
                unsigned int q1 = (unsigned int)(fmaxf(-n1, 0.f) * FPSCALE + 0.5f);
                unsigned int q2 = (unsigned int)(fmaxf(-n2, 0.f) * FPSCALE + 0.5f);
                unsigned int q3 = (unsigned int)(fmaxf(-n3, 0.f) * FPSCALE + 0.5f);
                atomicAdd(&agg8[(long)dstv[u] * 8 + 2 * q],
                          (ull)q0 | ((ull)q1 << 32));
                atomicAdd(&agg8[(long)dstv[u] * 8 + 2 * q + 1],
                          (ull)q2 | ((ull)q3 << 32));

                // reverse message for next iteration: edge m^1 is lane m^1
                mo0[k] = __shfl_xor(pack_h(n0, n1), 1, 64);
                mo1[k] = __shfl_xor(pack_h(n2, n3), 1, 64);
            }
        }

        __threadfence();
        grid.sync();

        // ================= update phase =================
        float* dstp = (it == NITERS - 1) ? out : logb;
        for (int idx = tid; idx < NN * CC; idx += CNTHR) {
            unsigned int av = agg32[idx];
            agg32[idx] = 0u;                    // reset for next iteration
            float v = fmaf(-(float)av, FPINV, logb0[idx]);
            float mx = v;
            for (int off = 8; off; off >>= 1) mx = fmaxf(mx, __shfl_xor(mx, off, 16));
            float s = __expf(v - mx);
            for (int off = 8; off; off >>= 1) s += __shfl_xor(s, off, 16);
            dstp[idx] = v - mx - __logf(s);
        }

        if (it != NITERS - 1) {
            __threadfence();
            grid.sync();
        }
        curb = logb;
    }
}

// ---------------------------------------------------------------------------
// FALLBACK PATH — round-0 verified MFMA edge kernel (msg2 in HBM).
// ---------------------------------------------------------------------------
template <bool RD_MSG, bool WR_MSG>
__global__ __launch_bounds__(256) void k_edges_m(
    const int* __restrict__ esrc, const int* __restrict__ edst,
    const float* __restrict__ logb, const float* __restrict__ Mg,
    unsigned int* __restrict__ msg2, ull* __restrict__ agg8)
{
    const int lane = threadIdx.x & 63;
    const int wid  = blockIdx.x * 4 + (threadIdx.x >> 6);
    const int m    = lane & 15;      // input: edge row; output: class col
    const int q    = lane >> 4;      // input: k-quad;  output: row group

#if USE_1K
    v4s bfrag;
#pragma unroll
    for (int j = 0; j < 4; ++j)
        bfrag[j] = (short)f2bf(Mg[(4 * q + j) * CC + m]);
    f4 rs = *(const f4*)(Mg + 256 + 4 * q);

    int src[UU];
    i4v d4[UU];
    u4v mw[UU];
    f4  lb[UU];
#pragma unroll
    for (int u = 0; u < UU; ++u) {
        const long eb = (long)(wid * UU + u) * 16;
        src[u] = __builtin_nontemporal_load(esrc + eb + m);
        d4[u]  = *(const i4v*)(edst + eb + 4 * q);
    }
#pragma unroll
    for (int u = 0; u < UU; ++u) {
        const long p = (long)(wid * UU + u) * 8 + (m >> 1);
        if (RD_MSG)
            mw[u] = __builtin_nontemporal_load((const u4v*)(msg2 + p * CC + 4 * q));
        lb[u] = *(const f4*)(logb + (long)src[u] * CC + 4 * q);
    }

#pragma unroll
    for (int u = 0; u < UU; ++u) {
        const long pb = (long)(wid * UU + u) * 8;

        float e[4], Tm = 0.f;
#pragma unroll
        for (int j = 0; j < 4; ++j) {
            float mo = NEGLOGC;
            if (RD_MSG)
                mo = (m & 1) ? h2f((unsigned short)(mw[u][j] & 0xffffu))
                             : h2f((unsigned short)(mw[u][j] >> 16));
            e[j] = __expf(lb[u][j] - mo);
            Tm   = fmaf(e[j], rs[j], Tm);
        }
        Tm += __shfl_xor(Tm, 16, 64);
        Tm += __shfl_xor(Tm, 32, 64);
        float ltA = __logf(Tm);

        v4s a;
#pragma unroll
        for (int j = 0; j < 4; ++j) a[j] = (short)f2bf(e[j]);
        v4f acc = {0.f, 0.f, 0.f, 0.f};
        v4f D = __builtin_amdgcn_mfma_f32_16x16x16bf16_1k(a, bfrag, acc, 0, 0, 0);

        float n[4];
#pragma unroll
        for (int i = 0; i < 4; ++i) {
            float lT = __shfl(ltA, 4 * q + i, 16);
            n[i] = __logf(D[i]) - lT;
        }

        if (WR_MSG) {
            __builtin_nontemporal_store(pack_h(n[0], n[1]),
                                        msg2 + (pb + 2 * q) * CC + m);
            __builtin_nontemporal_store(pack_h(n[2], n[3]),
                                        msg2 + (pb + 2 * q + 1) * CC + m);
        }

#pragma unroll
        for (int i = 0; i < 4; ++i) {
            unsigned int qv = (unsigned int)(fmaxf(-n[i], 0.f) * FPSCALE + 0.5f);
            unsigned int pv = __shfl_xor(qv, 1, 16);
            if (!(m & 1)) {
                ull val = (ull)qv | ((ull)pv << 32);
                atomicAdd(&agg8[(long)d4[u][i] * 8 + (m >> 1)], val);
            }
        }
    }
#else
    v8s bfrag = {0, 0, 0, 0, 0, 0, 0, 0};
    if (q < 2) {
#pragma unroll
        for (int j = 0; j < 8; ++j)
            bfrag[j] = (short)f2bf(Mg[(8 * q + j) * CC + m]);
    }
#pragma unroll
    for (int u = 0; u < UU; ++u) {
        const int  blk = wid * UU + u;
        const long eb  = (long)blk * 16;
        const long pb  = (long)blk * 8;
        const long p   = pb + (m >> 1);
        int src = __builtin_nontemporal_load(esrc + eb + m);
        v8s a = {0, 0, 0, 0, 0, 0, 0, 0};
        if (q < 2) {
            f4 lbA = *(const f4*)(logb + (long)src * CC + 8 * q);
            f4 lbB = *(const f4*)(logb + (long)src * CC + 8 * q + 4);
            float mo[8];
            if (RD_MSG) {
                u4v mwA = __builtin_nontemporal_load((const u4v*)(msg2 + p * CC + 8 * q));
                u4v mwB = __builtin_nontemporal_load((const u4v*)(msg2 + p * CC + 8 * q + 4));
#pragma unroll
                for (int j = 0; j < 4; ++j) {
                    mo[j]     = (m & 1) ? h2f((unsigned short)(mwA[j] & 0xffffu))
                                        : h2f((unsigned short)(mwA[j] >> 16));
                    mo[4 + j] = (m & 1) ? h2f((unsigned short)(mwB[j] & 0xffffu))
                                        : h2f((unsigned short)(mwB[j] >> 16));
                }
            } else {
#pragma unroll
                for (int j = 0; j < 8; ++j) mo[j] = NEGLOGC;
            }
#pragma unroll
            for (int j = 0; j < 4; ++j) {
                a[j]     = (short)f2bf(__expf(lbA[j] - mo[j]));
                a[4 + j] = (short)f2bf(__expf(lbB[j] - mo[4 + j]));
            }
        }
        v4f acc = {0.f, 0.f, 0.f, 0.f};
        v4f D = __builtin_amdgcn_mfma_f32_16x16x32_bf16(a, bfrag, acc, 0, 0, 0);
        v4f T = D;
#pragma unroll
        for (int off = 1; off < 16; off <<= 1) {
#pragma unroll
            for (int i = 0; i < 4; ++i) T[i] += __shfl_xor(T[i], off, 16);
        }
        float n[4];
#pragma unroll
        for (int i = 0; i < 4; ++i) n[i] = __logf(D[i]) - __logf(T[i]);
        if (WR_MSG) {
            __builtin_nontemporal_store(pack_h(n[0], n[1]), msg2 + (pb + 2 * q) * CC + m);
            __builtin_nontemporal_store(pack_h(n[2], n[3]), msg2 + (pb + 2 * q + 1) * CC + m);
        }
        i4v d4 = *(const i4v*)(edst + eb + 4 * q);
#pragma unroll
        for (int i = 0; i < 4; ++i) {
            unsigned int qv = (unsigned int)(fmaxf(-n[i], 0.f) * FPSCALE + 0.5f);
            unsigned int pv = __shfl_xor(qv, 1, 16);
            if (!(m & 1)) {
                ull val = (ull)qv | ((ull)pv << 32);
                atomicAdd(&agg8[(long)d4[i] * 8 + (m >> 1)], val);
            }
        }
    }
#endif
}

__global__ __launch_bounds__(256) void k_update(
    const float* __restrict__ logb0, unsigned int* __restrict__ agg32,
    float* __restrict__ out)
{
    int idx = blockIdx.x * blockDim.x + threadIdx.x;
    unsigned int q = agg32[idx];
    agg32[idx] = 0u;
    float v = fmaf(-(float)q, FPINV, logb0[idx]);
    float m = v;
    for (int off = 8; off; off >>= 1) m = fmaxf(m, __shfl_xor(m, off, 16));
    float s = __expf(v - m);
    for (int off = 8; off; off >>= 1) s += __shfl_xor(s, off, 16);
    out[idx] = v - m - __logf(s);
}

// ---------------------------------------------------------------------------
extern "C" void kernel_launch(void* const* d_in, const int* in_sizes, int n_in,
                              void* d_out, int out_size, void* d_ws, size_t ws_size,
                              hipStream_t stream)
{
    const float* x     = (const float*)d_in[0];
    const float* W     = (const float*)d_in[1];
    const float* b     = (const float*)d_in[2];
    const float* param = (const float*)d_in[3];
    const int*   eidx  = (const int*)d_in[4];
    const int*   esrc  = eidx;
    const int*   edst  = eidx + EE;

    float* ws    = (float*)d_ws;
    float* M     = ws;                         // 256 + 16 rowsums (pad 288)
    float* logb0 = M     + 288;                // N*C
    float* logb  = logb0 + (long)NN * CC;      // N*C
    unsigned int* agg32 = (unsigned int*)(logb + (long)NN * CC);  // N*C u32
    ull*          agg8  = (ull*)agg32;
    unsigned int* msg2  = agg32 + (long)NN * CC;                  // NPAIRS*C u32
    float* outp  = (float*)d_out;

    k_setup<<<NN * CC / 256, 256, 0, stream>>>(x, W, b, param, M, logb0, agg32);

    // ---- cooperative-path gate: decide once, on an uncaptured call ----
    static int coop_state = -1;   // -1 unknown, 1 validated, 0 unusable
    if (coop_state == -1) {
        hipStreamCaptureStatus cs = hipStreamCaptureStatusNone;
        (void)hipStreamIsCapturing(stream, &cs);
        if (cs == hipStreamCaptureStatusNone) {
            int dev = 0, coop = 0, ncu = 0, maxb = 0;
            (void)hipGetDevice(&dev);
            (void)hipDeviceGetAttribute(&coop, hipDeviceAttributeCooperativeLaunch, dev);
            (void)hipDeviceGetAttribute(&ncu, hipDeviceAttributeMultiprocessorCount, dev);
            hipError_t oe = hipOccupancyMaxActiveBlocksPerMultiprocessor(
                &maxb, (const void*)k_bp, 256, 0);
            if (coop && oe == hipSuccess && (long)maxb * (long)ncu >= CPBLK) {
                void* kargs[] = { (void*)&esrc, (void*)&edst, (void*)&logb0,
                                  (void*)&M, (void*)&agg32, (void*)&logb,
                                  (void*)&outp };
                hipError_t rc = hipLaunchCooperativeKernel(
                    (void*)k_bp, dim3(CPBLK), dim3(256), kargs, 0u, stream);
                coop_state = (rc == hipSuccess) ? 1 : 0;
                if (coop_state == 1) return;
            } else {
                coop_state = 0;
            }
        }
        // capturing with undecided state: fall through to fallback this call
    } else if (coop_state == 1) {
        void* kargs[] = { (void*)&esrc, (void*)&edst, (void*)&logb0,
                          (void*)&M, (void*)&agg32, (void*)&logb,
                          (void*)&outp };
        hipError_t rc = hipLaunchCooperativeKernel(
            (void*)k_bp, dim3(CPBLK), dim3(256), kargs, 0u, stream);
        if (rc == hipSuccess) return;
        coop_state = 0;            // best effort: fall back below
    }

    // ---- fallback: round-0 verified multi-kernel pipeline ----
    const float* curb = logb0;
    for (int it = 0; it < NITERS; ++it) {
        if (it == 0)
            k_edges_m<false, true><<<GRID_E, 256, 0, stream>>>(
                esrc, edst, curb, M, msg2, agg8);
        else if (it == NITERS - 1)
            k_edges_m<true, false><<<GRID_E, 256, 0, stream>>>(
                esrc, edst, curb, M, msg2, agg8);
        else
            k_edges_m<true, true><<<GRID_E, 256, 0, stream>>>(
                esrc, edst, curb, M, msg2, agg8);
        float* dst = (it == NITERS - 1) ? outp : logb;
        k_update<<<NN * CC / 256, 256, 0, stream>>>(logb0, agg32, dst);
        curb = dst;
    }
}